// Round 15
// baseline (298.429 us; speedup 1.0000x reference)
//
#include <hip/hip_runtime.h>
#include <stdint.h>

typedef __bf16 bf16;
typedef __bf16 bf16x4 __attribute__((ext_vector_type(4)));
typedef __bf16 bf16x8 __attribute__((ext_vector_type(8)));
typedef float  f32x4  __attribute__((ext_vector_type(4)));

#define DEVI __device__ __forceinline__

DEVI void gll16(const void* g, void* l) {
  __builtin_amdgcn_global_load_lds(
      (const __attribute__((address_space(1))) void*)g,
      (__attribute__((address_space(3))) void*)l,
      16, 0, 0);
}

DEVI f32x4 mfma16(bf16x8 a, bf16x8 b, f32x4 c) {
  return __builtin_amdgcn_mfma_f32_16x16x32_bf16(a, b, c, 0, 0, 0);
}

// ------------- weight transpose body: fp32 [K][N] -> bf16 W^T [N][K], 64x64 tile -------------
DEVI void wt_body(char* arena, const float* __restrict__ W, bf16* __restrict__ WT,
                  int K, int N, int bx, int by, int tid) {
  float (*t)[65] = reinterpret_cast<float(*)[65]>(arena);   // 64x65 fp32 = 16640 B
  int bn = bx * 64, bk = by * 64;
  int tx = tid & 63, ty = tid >> 6;
#pragma unroll
  for (int i = 0; i < 16; ++i)
    t[ty + i * 4][tx] = W[(size_t)(bk + ty + i * 4) * N + bn + tx];
  __syncthreads();
#pragma unroll
  for (int i = 0; i < 16; ++i)
    WT[(size_t)(bn + ty + i * 4) * K + bk + tx] = (bf16)t[tx][ty + i * 4];
}

// ---------------- layernorm body (C=1024) fp32 -> bf16 ----------------
DEVI void ln_body(char* arena, const float* __restrict__ x, const float* __restrict__ g,
                  const float* __restrict__ b, bf16* __restrict__ out, int row, int tid) {
  float* ps  = (float*)arena;
  float* psq = ps + 4;
  f32x4 v = ((const f32x4*)(x + (size_t)row * 1024))[tid];
  float s = v[0] + v[1] + v[2] + v[3];
  float sq = v[0]*v[0] + v[1]*v[1] + v[2]*v[2] + v[3]*v[3];
#pragma unroll
  for (int m = 1; m < 64; m <<= 1) {
    s  += __shfl_xor(s, m, 64);
    sq += __shfl_xor(sq, m, 64);
  }
  int w = tid >> 6;
  if ((tid & 63) == 0) { ps[w] = s; psq[w] = sq; }
  __syncthreads();
  s  = ps[0] + ps[1] + ps[2] + ps[3];
  sq = psq[0] + psq[1] + psq[2] + psq[3];
  float mean = s * (1.f / 1024.f);
  float rs = rsqrtf(sq * (1.f / 1024.f) - mean * mean + 1e-5f);
  f32x4 gv = ((const f32x4*)g)[tid];
  f32x4 bv = ((const f32x4*)b)[tid];
  bf16x4 o;
#pragma unroll
  for (int i = 0; i < 4; ++i) o[i] = (bf16)((v[i] - mean) * rs * gv[i] + bv[i]);
  ((bf16x4*)(out + (size_t)row * 1024))[tid] = o;
}

__global__ __launch_bounds__(256)
void k_ln(const float* __restrict__ x, const float* __restrict__ g,
          const float* __restrict__ b, bf16* __restrict__ out) {
  __shared__ __align__(16) char arena[64];
  ln_body(arena, x, g, b, out, blockIdx.x, threadIdx.x);
}

// D1: ln1 (4096) + c_attn^T (768) + plan conv (1024) + bias concat (8)
//     + k^T (256) + v^T (256) + q^T (256)
__global__ __launch_bounds__(256)
void mega_misc(const float* __restrict__ x, const float* __restrict__ g,
               const float* __restrict__ b, bf16* __restrict__ out,
               const float* __restrict__ W, bf16* __restrict__ WT,
               const float* __restrict__ plan, bf16* __restrict__ planb,
               const float* __restrict__ kb, const float* __restrict__ vb,
               float* __restrict__ biaskv,
               const float* __restrict__ kw, bf16* __restrict__ kwt,
               const float* __restrict__ vw, bf16* __restrict__ vwt,
               const float* __restrict__ qw, bf16* __restrict__ qwt) {
  __shared__ __align__(16) char arena[16640];
  const int bid = blockIdx.x, tid = threadIdx.x;
  if (bid < 4096) {
    ln_body(arena, x, g, b, out, bid, tid);
  } else if (bid < 4864) {
    int wid = bid - 4096;
    wt_body(arena, W, WT, 1024, 3072, wid % 48, wid / 48, tid);
  } else if (bid < 5888) {
    int i = (bid - 4864) * 256 + tid;
    f32x4 v = ((const f32x4*)plan)[i];
    bf16x4 o;
    o[0] = (bf16)v[0]; o[1] = (bf16)v[1]; o[2] = (bf16)v[2]; o[3] = (bf16)v[3];
    ((bf16x4*)planb)[i] = o;
  } else if (bid < 5896) {
    int i = (bid - 5888) * 256 + tid;
    biaskv[i] = i < 1024 ? kb[i] : vb[i - 1024];
  } else if (bid < 6152) {
    int wid = bid - 5896;
    wt_body(arena, kw, kwt, 1024, 1024, wid & 15, wid >> 4, tid);
  } else if (bid < 6408) {
    int wid = bid - 6152;
    wt_body(arena, vw, vwt, 1024, 1024, wid & 15, wid >> 4, tid);
  } else {
    int wid = bid - 6408;
    wt_body(arena, qw, qwt, 1024, 1024, wid & 15, wid >> 4, tid);
  }
}

// ---------------- GEMM small-tile body: BM=64 BN=128 BK=64, 2-phase ----------------
// EPI 0: bf16 out.  EPI 1: fp32 out += v.  EPI 2: gelu->bf16.  EPI 3: out = Xres + v.
template <int EPI>
DEVI void gemm_s_body(char* arena, const bf16* __restrict__ A, const bf16* __restrict__ BT,
                      const float* __restrict__ bias, void* __restrict__ Cout,
                      int M, int N, int K, const float* __restrict__ Xres,
                      int nwg, int bid) {
  char (*SA)[8192]  = reinterpret_cast<char(*)[8192]>(arena);
  char (*SB)[16384] = reinterpret_cast<char(*)[16384]>(arena + 16384);
  const int tid = threadIdx.x;
  const int lane = tid & 63;
  const int w = tid >> 6;
  const int wr = w >> 1, wc = w & 1;
  const int lr = lane & 15, lg = lane >> 4;
  const int nk = K >> 6;

  const int q = nwg >> 3, r = nwg & 7;
  const int xcd = bid & 7, loc = bid >> 3;
  const int wg = (xcd < r ? xcd * (q + 1) : r * (q + 1) + (xcd - r) * q) + loc;
  const int gy = M >> 6;
  const int m0 = (wg % gy) << 6, n0 = (wg / gy) << 7;

  const int c8 = tid & 7;
  const int hrb = tid >> 3;
  auto stgA = [&](int buf, int ktc) {
#pragma unroll
    for (int i = 0; i < 2; ++i) {
      int hr = i * 32 + hrb;
      const bf16* s = A + (size_t)(m0 + hr) * K + ((size_t)ktc << 6) + ((c8 ^ (hr & 7)) << 3);
      gll16(s, &SA[buf][(i * 256 + tid) * 16]);
    }
  };
  auto stgB = [&](int buf, int ktc) {
#pragma unroll
    for (int i = 0; i < 4; ++i) {
      int hr = i * 32 + hrb;
      const bf16* s = BT + (size_t)(n0 + hr) * K + ((size_t)ktc << 6) + ((c8 ^ (hr & 7)) << 3);
      gll16(s, &SB[buf][(i * 256 + tid) * 16]);
    }
  };
  auto rdf = [&](const char* base, int rloc, int ks) -> bf16x8 {
    return *(const bf16x8*)(base + rloc * 128 + (((ks << 6) + (lg << 4)) ^ ((rloc & 7) << 4)));
  };

  f32x4 acc[2][4] = {};

  stgA(0, 0); stgB(0, 0);
  __syncthreads();
  for (int kt = 0; kt < nk; ++kt) {
    const int cur = kt & 1;
    if (kt + 1 < nk) { stgA(cur ^ 1, kt + 1); stgB(cur ^ 1, kt + 1); }
    bf16x8 af[2][2], bfr[4][2];
#pragma unroll
    for (int i = 0; i < 2; ++i)
#pragma unroll
      for (int ks = 0; ks < 2; ++ks)
        af[i][ks] = rdf(SA[cur], wr * 32 + i * 16 + lr, ks);
#pragma unroll
    for (int j = 0; j < 4; ++j)
#pragma unroll
      for (int ks = 0; ks < 2; ++ks)
        bfr[j][ks] = rdf(SB[cur], wc * 64 + j * 16 + lr, ks);
#pragma unroll
    for (int i = 0; i < 2; ++i)
#pragma unroll
      for (int j = 0; j < 4; ++j)
#pragma unroll
        for (int ks = 0; ks < 2; ++ks)
          acc[i][j] = mfma16(af[i][ks], bfr[j][ks], acc[i][j]);
    __syncthreads();
  }

  float* of = (float*)Cout;
  bf16*  ob = (bf16*)Cout;
#pragma unroll
  for (int j = 0; j < 4; ++j) {
    int gn = n0 + wc * 64 + j * 16 + lr;
    float bv = bias[gn];
#pragma unroll
    for (int i = 0; i < 2; ++i) {
      int gmb = m0 + wr * 32 + i * 16 + lg * 4;
#pragma unroll
      for (int rr = 0; rr < 4; ++rr) {
        size_t idx = (size_t)(gmb + rr) * N + gn;
        float v = acc[i][j][rr] + bv;
        if (EPI == 0) ob[idx] = (bf16)v;
        else if (EPI == 1) of[idx] += v;
        else if (EPI == 3) of[idx] = Xres[idx] + v;
        else {
          float ge = 0.5f * v * (1.f + erff(v * 0.70710678f));
          ob[idx] = (bf16)ge;
        }
      }
    }
  }
}

template <int EPI>
__global__ __launch_bounds__(256, 3)
void k_gemm_s(const bf16* __restrict__ A, const bf16* __restrict__ BT,
              const float* __restrict__ bias, void* __restrict__ Cout,
              int M, int N, int K, const float* __restrict__ Xres) {
  __shared__ __align__(16) char arena[49152];
  gemm_s_body<EPI>(arena, A, BT, bias, Cout, M, N, K, Xres, gridDim.x, blockIdx.x);
}

// D6: qx-gemm (512) + kv-gemm (256) — mutually independent
__global__ __launch_bounds__(256, 3)
void mega_gemmC2(const bf16* __restrict__ Aq, const bf16* __restrict__ qwt,
                 const float* __restrict__ qb, void* __restrict__ qxo,
                 const bf16* __restrict__ Ap, const bf16* __restrict__ kwt,
                 const float* __restrict__ bkv, void* __restrict__ kvo) {
  __shared__ __align__(16) char arena[49152];
  if ((int)blockIdx.x < 512) {
    gemm_s_body<0>(arena, Aq, qwt, qb, qxo, 4096, 1024, 1024, nullptr, 512, blockIdx.x);
  } else {
    gemm_s_body<0>(arena, Ap, kwt, bkv, kvo, 1024, 2048, 1024, nullptr, 256, blockIdx.x - 512);
  }
}

// D8: ca-gemm (512) + mlp_proj weight transpose (1024, K=4096)
__global__ __launch_bounds__(256, 3)
void mega_gemmB2(const bf16* __restrict__ A, const bf16* __restrict__ BT,
                 const float* __restrict__ bias, void* __restrict__ Cout,
                 const float* __restrict__ mw, bf16* __restrict__ mwt) {
  __shared__ __align__(16) char arena[49152];
  if ((int)blockIdx.x < 512) {
    gemm_s_body<1>(arena, A, BT, bias, Cout, 4096, 1024, 1024, nullptr, 512, blockIdx.x);
  } else {
    int wid = blockIdx.x - 512;
    wt_body(arena, mw, mwt, 4096, 1024, wid & 15, wid >> 4, threadIdx.x);
  }
}

// ---------------- GEMM 256x256 8-phase counted-vmcnt ----------------
template <int EPI>
__global__ __launch_bounds__(512, 2)
void k_gemm8(const bf16* __restrict__ A, const bf16* __restrict__ BT,
             const float* __restrict__ bias, void* __restrict__ Cout,
             int M, int N, int K) {
  __shared__ __align__(16) char SA[2][2][16384];
  __shared__ __align__(16) char SB[2][2][16384];
  const int tid = threadIdx.x;
  const int lane = tid & 63;
  const int w = tid >> 6;
  const int wm = w >> 2, wn = w & 3;
  const int lr = lane & 15, lg = lane >> 4;
  const int nk = K >> 6;

  const int nwg = gridDim.x;
  const int q = nwg >> 3, r = nwg & 7;
  const int xcd = blockIdx.x & 7, loc = blockIdx.x >> 3;
  const int wg = (xcd < r ? xcd * (q + 1) : r * (q + 1) + (xcd - r) * q) + loc;
  const int gy = M >> 8;
  const int m0 = (wg % gy) << 8, n0 = (wg / gy) << 8;

  const int c8 = tid & 7;
  auto stg = [&](char* dst, const bf16* src0, int base0, int half, int ktc) {
#pragma unroll
    for (int i = 0; i < 2; ++i) {
      int hr = i * 64 + (tid >> 3);
      const bf16* s = src0 + (size_t)(base0 + half * 128 + hr) * K + ((size_t)ktc << 6)
                    + ((c8 ^ (hr & 7)) << 3);
      gll16(s, dst + (i * 512 + tid) * 16);
    }
  };
  auto rdf = [&](const char* hbase, int rloc, int ks) -> bf16x8 {
    return *(const bf16x8*)(hbase + rloc * 128 + (((ks << 6) + (lg << 4)) ^ ((rloc & 7) << 4)));
  };

  f32x4 acc[8][4] = {};
  bf16x8 af[4][2], b0f[2][2], b1f[2][2];

  stg(SA[0][0], A, m0, 0, 0);
  stg(SB[0][0], BT, n0, 0, 0);
  stg(SB[0][1], BT, n0, 1, 0);
  stg(SA[0][1], A, m0, 1, 0);
  stg(SA[1][0], A, m0, 0, 1);
  stg(SB[1][0], BT, n0, 0, 1);
  asm volatile("s_waitcnt vmcnt(8)" ::: "memory");
  __builtin_amdgcn_s_barrier();

  for (int kt = 0; kt < nk; ++kt) {
    const int cur = kt & 1;
    const char* hA0 = SA[cur][0]; const char* hA1 = SA[cur][1];
    const char* hB0 = SB[cur][0]; const char* hB1 = SB[cur][1];
    const int tn  = (kt + 1 < nk) ? kt + 1 : nk - 1;
    const int tn2 = (kt + 2 < nk) ? kt + 2 : nk - 1;

    stg(SB[(kt + 1) & 1][1], BT, n0, 1, tn);
    asm volatile("s_waitcnt vmcnt(8)" ::: "memory");
#pragma unroll
    for (int i = 0; i < 4; ++i) {
      int rl = i * 32 + wm * 16 + lr;
#pragma unroll
      for (int ks = 0; ks < 2; ++ks) af[i][ks] = rdf(hA0, rl, ks);
    }
#pragma unroll
    for (int j = 0; j < 2; ++j) {
      int rl = j * 64 + wn * 16 + lr;
#pragma unroll
      for (int ks = 0; ks < 2; ++ks) b0f[j][ks] = rdf(hB0, rl, ks);
    }
    __builtin_amdgcn_s_barrier();
    __builtin_amdgcn_s_setprio(1);
#pragma unroll
    for (int i = 0; i < 4; ++i)
#pragma unroll
      for (int j = 0; j < 2; ++j)
#pragma unroll
        for (int ks = 0; ks < 2; ++ks)
          acc[i][j] = mfma16(af[i][ks], b0f[j][ks], acc[i][j]);
    __builtin_amdgcn_s_setprio(0);

    stg(SA[(kt + 1) & 1][1], A, m0, 1, tn);
    asm volatile("s_waitcnt vmcnt(8)" ::: "memory");
#pragma unroll
    for (int j = 0; j < 2; ++j) {
      int rl = j * 64 + wn * 16 + lr;
#pragma unroll
      for (int ks = 0; ks < 2; ++ks) b1f[j][ks] = rdf(hB1, rl, ks);
    }
    __builtin_amdgcn_s_barrier();
    __builtin_amdgcn_s_setprio(1);
#pragma unroll
    for (int i = 0; i < 4; ++i)
#pragma unroll
      for (int j = 0; j < 2; ++j)
#pragma unroll
        for (int ks = 0; ks < 2; ++ks)
          acc[i][2 + j] = mfma16(af[i][ks], b1f[j][ks], acc[i][2 + j]);
    __builtin_amdgcn_s_setprio(0);

    stg(SA[cur][0], A, m0, 0, tn2);
#pragma unroll
    for (int i = 0; i < 4; ++i) {
      int rl = i * 32 + wm * 16 + lr;
#pragma unroll
      for (int ks = 0; ks < 2; ++ks) af[i][ks] = rdf(hA1, rl, ks);
    }
    __builtin_amdgcn_s_barrier();
    __builtin_amdgcn_s_setprio(1);
#pragma unroll
    for (int i = 0; i < 4; ++i)
#pragma unroll
      for (int j = 0; j < 2; ++j)
#pragma unroll
        for (int ks = 0; ks < 2; ++ks)
          acc[4 + i][j] = mfma16(af[i][ks], b0f[j][ks], acc[4 + i][j]);
    __builtin_amdgcn_s_setprio(0);

    stg(SB[cur][0], BT, n0, 0, tn2);
    asm volatile("s_waitcnt vmcnt(8)" ::: "memory");
    __builtin_amdgcn_s_barrier();
    __builtin_amdgcn_s_setprio(1);
#pragma unroll
    for (int i = 0; i < 4; ++i)
#pragma unroll
      for (int j = 0; j < 2; ++j)
#pragma unroll
        for (int ks = 0; ks < 2; ++ks)
          acc[4 + i][2 + j] = mfma16(af[i][ks], b1f[j][ks], acc[4 + i][2 + j]);
    __builtin_amdgcn_s_setprio(0);
  }

  float* of = (float*)Cout;
  bf16*  ob = (bf16*)Cout;
#pragma unroll
  for (int ni = 0; ni < 4; ++ni) {
    int gn = n0 + (ni >> 1) * 128 + (ni & 1) * 64 + wn * 16 + lr;
    float bv = bias[gn];
#pragma unroll
    for (int mi = 0; mi < 8; ++mi) {
      int gmb = m0 + (mi >> 2) * 128 + (mi & 3) * 32 + wm * 16 + lg * 4;
#pragma unroll
      for (int rr = 0; rr < 4; ++rr) {
        size_t idx = (size_t)(gmb + rr) * N + gn;
        float v = acc[mi][ni][rr] + bv;
        if (EPI == 0) ob[idx] = (bf16)v;
        else if (EPI == 1) of[idx] += v;
        else {
          float ge = 0.5f * v * (1.f + erff(v * 0.70710678f));
          ob[idx] = (bf16)ge;
        }
      }
    }
  }
}

// ---------------- fused flash attention body (r4 champion logic) ----------------
template <bool CAUSAL>
DEVI void attn_body(char* arena, int id,
                    const bf16* __restrict__ Qb, int ldq, int qcol0,
                    const bf16* __restrict__ Kb, int kcol0,
                    const bf16* __restrict__ Vb, int vcol0,
                    int ldkv, int qlen, int kvlen,
                    bf16* __restrict__ Ob, int ldo, float scale) {
  char (*Klds)[8192]   = reinterpret_cast<char(*)[8192]>(arena);
  bf16 (*VT)[64][68]   = reinterpret_cast<bf16(*)[64][68]>(arena + 16384);
  const int tid = threadIdx.x;
  const int lane = tid & 63;
  const int w = tid >> 6;
  const int lr = lane & 15, lg = lane >> 4;

  int h, b, qt;
  if (CAUSAL) {
    int low = id & 255;
    h = low & 15; b = (low >> 4) & 1;
    int q3 = low >> 5;
    qt = (id >> 8) ? (8 + q3) : (7 - q3);
  } else {
    h = id & 15; b = (id >> 4) & 1; qt = id >> 5;
  }

  const int qbase = qt * 128;
  const int kvbase = b * kvlen;
  const int nkv = CAUSAL ? (2 * qt + 2) : (kvlen >> 6);
  const int mask_from = CAUSAL ? (nkv - 2) : 0x7fffffff;

  bf16x8 qf[2][2];
#pragma unroll
  for (int g = 0; g < 2; ++g)
#pragma unroll
    for (int kk = 0; kk < 2; ++kk)
      qf[g][kk] = *(const bf16x8*)(Qb + (size_t)(b * qlen + qbase + w * 32 + g * 16 + lr) * ldq
                                   + qcol0 + h * 64 + kk * 32 + lg * 8);

  f32x4 o[2][4] = {};
  float mrun[2] = {-3.0e38f, -3.0e38f};
  float lsum[2] = {0.f, 0.f};

  bf16x8 vr0, vr1;
  const int vkv = lane;
  const int vd0 = (tid >> 6) * 16;
  const bf16* Vbase = Vb + vcol0 + h * 64 + vd0;

  auto stageK = [&](int buf, int kvt) {
#pragma unroll
    for (int t = 0; t < 2; ++t) {
      int r = t * 32 + (tid >> 3);
      int pb = (tid & 7) * 16;
      const char* gs = (const char*)(Kb + (size_t)(kvbase + kvt * 64 + r) * ldkv + kcol0 + h * 64)
                       + (pb ^ ((r & 7) << 4));
      gll16(gs, &Klds[buf][t * 4096 + tid * 16]);
    }
  };
  auto loadV = [&](int kvt) {
    const bf16* vp = Vbase + (size_t)(kvbase + kvt * 64 + vkv) * ldkv;
    vr0 = *(const bf16x8*)vp;
    vr1 = *(const bf16x8*)(vp + 8);
  };
  auto writeV = [&](int buf) {
#pragma unroll
    for (int i = 0; i < 8; ++i) VT[buf][vd0 + i][vkv] = vr0[i];
#pragma unroll
    for (int i = 0; i < 8; ++i) VT[buf][vd0 + 8 + i][vkv] = vr1[i];
  };

  stageK(0, 0);
  loadV(0);
  writeV(0);
  __syncthreads();

  int cur = 0;
  for (int kvt = 0; kvt < nkv; ++kvt) {
    if (kvt + 1 < nkv) { stageK(cur ^ 1, kvt + 1); loadV(kvt + 1); }

    f32x4 s[2][4] = {};
#pragma unroll
    for (int sub = 0; sub < 4; ++sub) {
      int row = sub * 16 + lr;
#pragma unroll
      for (int kk = 0; kk < 2; ++kk) {
        bf16x8 kf = *(const bf16x8*)&Klds[cur][(row << 7) + ((kk * 64 + lg * 16) ^ ((row & 7) << 4))];
        s[0][sub] = mfma16(kf, qf[0][kk], s[0][sub]);
        s[1][sub] = mfma16(kf, qf[1][kk], s[1][sub]);
      }
    }

    const bool domask = CAUSAL && (kvt >= mask_from);
    bf16x8 pa[2][2];
#pragma unroll
    for (int g = 0; g < 2; ++g) {
      const int qg = qbase + w * 32 + g * 16 + lr;
      float pmax = -3.0e38f;
#pragma unroll
      for (int sub = 0; sub < 4; ++sub)
#pragma unroll
        for (int j = 0; j < 4; ++j) {
          float v = s[g][sub][j] * scale;
          if (domask) {
            int kvg = kvt * 64 + sub * 16 + lg * 4 + j;
            if (kvg > qg) v = -3.0e38f;
          }
          s[g][sub][j] = v;
          pmax = fmaxf(pmax, v);
        }
      pmax = fmaxf(pmax, __shfl_xor(pmax, 16, 64));
      pmax = fmaxf(pmax, __shfl_xor(pmax, 32, 64));
      float mnew = mrun[g];
      if (__any(pmax - mrun[g] > 8.f)) {
        mnew = fmaxf(mrun[g], pmax);
        float alpha = __expf(mrun[g] - mnew);
        lsum[g] *= alpha;
        float al[4];
#pragma unroll
        for (int j = 0; j < 4; ++j) {
          int src = (lane & 48) | (lg * 4 + j);
          al[j] = __int_as_float(__builtin_amdgcn_ds_bpermute(src << 2, __float_as_int(alpha)));
        }
#pragma unroll
        for (int dt = 0; dt < 4; ++dt)
#pragma unroll
          for (int j = 0; j < 4; ++j) o[g][dt][j] *= al[j];
      }
      float psum = 0.f;
#pragma unroll
      for (int sub = 0; sub < 4; ++sub)
#pragma unroll
        for (int j = 0; j < 4; ++j) {
          float p = __expf(s[g][sub][j] - mnew);
          s[g][sub][j] = p;
          psum += p;
        }
      psum += __shfl_xor(psum, 16, 64);
      psum += __shfl_xor(psum, 32, 64);
      lsum[g] += psum;
      mrun[g] = mnew;
#pragma unroll
      for (int sp = 0; sp < 2; ++sp) {
#pragma unroll
        for (int j = 0; j < 4; ++j) {
          pa[g][sp][j]     = (bf16)s[g][2 * sp][j];
          pa[g][sp][4 + j] = (bf16)s[g][2 * sp + 1][j];
        }
      }
    }

#pragma unroll
    for (int sp = 0; sp < 2; ++sp) {
#pragma unroll
      for (int dt = 0; dt < 4; ++dt) {
        int d = dt * 16 + lr;
        bf16x4 va  = *(const bf16x4*)&VT[cur][d][sp * 32 + lg * 4];
        bf16x4 vb2 = *(const bf16x4*)&VT[cur][d][sp * 32 + 16 + lg * 4];
        bf16x8 vf = __builtin_shufflevector(va, vb2, 0, 1, 2, 3, 4, 5, 6, 7);
        o[0][dt] = mfma16(pa[0][sp], vf, o[0][dt]);
        o[1][dt] = mfma16(pa[1][sp], vf, o[1][dt]);
      }
    }

    if (kvt + 1 < nkv) writeV(cur ^ 1);
    __syncthreads();
    cur ^= 1;
  }

#pragma unroll
  for (int g = 0; g < 2; ++g) {
    float il[4];
#pragma unroll
    for (int j = 0; j < 4; ++j) {
      int src = (lane & 48) | (lg * 4 + j);
      float ls = __int_as_float(__builtin_amdgcn_ds_bpermute(src << 2, __float_as_int(lsum[g])));
      il[j] = 1.0f / ls;
    }
#pragma unroll
    for (int dt = 0; dt < 4; ++dt)
#pragma unroll
      for (int j = 0; j < 4; ++j) {
        int gq = b * qlen + qbase + w * 32 + g * 16 + lg * 4 + j;
        Ob[(size_t)gq * ldo + h * 64 + dt * 16 + lr] = (bf16)(o[g][dt][j] * il[j]);
      }
  }
}

// mega: attention (512) + wt1 1024x1024 (256) + optional wt2 1024x4096 (1024)
template <bool CAUSAL, bool WT2>
__global__ __launch_bounds__(256)
void mega_attn_wt(const bf16* __restrict__ Qb, int ldq, int qcol0,
                  const bf16* __restrict__ Kb, int kcol0,
                  const bf16* __restrict__ Vb, int vcol0,
                  int ldkv, int qlen, int kvlen,
                  bf16* __restrict__ Ob, int ldo, float scale,
                  const float* __restrict__ W1, bf16* __restrict__ WT1,
                  const float* __restrict__ W2, bf16* __restrict__ WT2b) {
  __shared__ __align__(16) char arena[33792];
  if ((int)blockIdx.x < 512) {
    attn_body<CAUSAL>(arena, blockIdx.x, Qb, ldq, qcol0, Kb, kcol0, Vb, vcol0,
                      ldkv, qlen, kvlen, Ob, ldo, scale);
  } else if ((int)blockIdx.x < 768) {
    int wid = blockIdx.x - 512;
    wt_body(arena, W1, WT1, 1024, 1024, wid & 15, wid >> 4, threadIdx.x);
  } else if (WT2) {
    int wid = blockIdx.x - 768;
    wt_body(arena, W2, WT2b, 1024, 4096, wid & 63, wid >> 6, threadIdx.x);
  }
}

// ---------------- host orchestration ----------------
extern "C" void kernel_launch(void* const* d_in, const int* in_sizes, int n_in,
                              void* d_out, int out_size, void* d_ws, size_t ws_size,
                              hipStream_t stream) {
  (void)in_sizes; (void)n_in; (void)out_size; (void)ws_size;
  const float* x        = (const float*)d_in[0];
  const float* plan     = (const float*)d_in[1];
  const float* ln1_g    = (const float*)d_in[2];
  const float* ln1_b    = (const float*)d_in[3];
  const float* c_attn_w = (const float*)d_in[4];
  const float* c_attn_b = (const float*)d_in[5];
  const float* aproj_w  = (const float*)d_in[6];
  const float* aproj_b  = (const float*)d_in[7];
  const float* ln2_g    = (const float*)d_in[8];
  const float* ln2_b    = (const float*)d_in[9];
  const float* q_w      = (const float*)d_in[10];
  const float* q_b      = (const float*)d_in[11];
  const float* k_w      = (const float*)d_in[12];
  const float* k_b      = (const float*)d_in[13];
  const float* v_w      = (const float*)d_in[14];
  const float* v_b      = (const float*)d_in[15];
  const float* ca_w     = (const float*)d_in[16];
  const float* ca_b     = (const float*)d_in[17];
  const float* ln3_g    = (const float*)d_in[18];
  const float* ln3_b    = (const float*)d_in[19];
  const float* fc_w     = (const float*)d_in[20];
  const float* fc_b     = (const float*)d_in[21];
  const float* mp_w     = (const float*)d_in[22];
  const float* mp_b     = (const float*)d_in[23];

  char* ws = (char*)d_ws;
  // ws layout (MiB):
  // [0-8)  wbuf : c_attn^T (D1-D2), then fc^T (D3-D10)
  // [8-16) lnb  : ln1 (D1-D2); aproj^T at +0-2 (D3-D4); ln2 (D5-D6); ln3 (D9-D10)
  // [16-17) planb (D1-D6)
  // [18-26) yb : self-attn out (D3-D4); qx (D6-D7); mp^T (D8-D11)
  // [26-58) rega: qkv 0-24 (D2-D3); kvc 0-4 (D6-D7); ca^T 4-6 (D7-D8);
  //         co 8-16 (D7-D8); k^T|v^T 24-28 (D1-D6); q^T 28-30 (D1-D6);
  //         hmid 0-32 (D10-D11)
  // [58+) biaskv
  bf16*  wbuf   = (bf16*)(ws);
  bf16*  lnb    = (bf16*)(ws + (8ull << 20));
  bf16*  planb  = (bf16*)(ws + (16ull << 20));
  bf16*  yb     = (bf16*)(ws + (18ull << 20));
  char*  rega   = ws + (26ull << 20);
  float* biaskv = (float*)(ws + (58ull << 20));
  bf16* qkv    = (bf16*)rega;
  bf16* kvc    = (bf16*)rega;                      // 4 MiB, D6->D7 (qkv dead)
  bf16* caT    = (bf16*)(rega + (4ull << 20));     // 2 MiB, D7->D8
  bf16* co     = (bf16*)(rega + (8ull << 20));     // 8 MiB, D7->D8
  bf16* kwt    = (bf16*)(rega + (24ull << 20));    // 2+2 MiB k^T|v^T, D1->D6
  bf16* qwt    = (bf16*)(rega + (28ull << 20));    // 2 MiB, D1->D6
  bf16* hmid   = (bf16*)rega;                      // 32 MiB, D10->D11
  bf16* aprojT = lnb;                              // 2 MiB, D3->D4
  bf16* fcT    = wbuf;                             // 8 MiB, D3->D10
  bf16* mpT    = yb;                               // 8 MiB, D8->D11
  float* xw = (float*)d_out;

  // D1: ln1 || c_attn^T || plan conv || bias concat || k^T || v^T || q^T
  mega_misc<<<6664, 256, 0, stream>>>(x, ln1_g, ln1_b, lnb, c_attn_w, wbuf,
                                      plan, planb, k_b, v_b, biaskv,
                                      k_w, kwt, v_w, kwt + (1u << 20), q_w, qwt);
  // D2: qkv gemm
  k_gemm8<0><<<192, 512, 0, stream>>>(lnb, wbuf, c_attn_b, qkv, 4096, 3072, 1024);
  // D3: causal attn || aproj^T(->lnb) || fc^T(->wbuf)
  mega_attn_wt<true, true><<<512 + 256 + 1024, 256, 0, stream>>>(
      qkv, 3072, 0, qkv, 1024, qkv, 2048, 3072, 2048, 2048, yb, 1024, 0.125f,
      aproj_w, aprojT, fc_w, fcT);
  // D4: aproj gemm (xw = x + yb*W) — pure, no riders
  k_gemm_s<3><<<512, 256, 0, stream>>>(yb, aprojT, aproj_b, xw, 4096, 1024, 1024, x);
  // D5: ln2
  k_ln<<<4096, 256, 0, stream>>>(xw, ln2_g, ln2_b, lnb);
  // D6: qx gemm (lnb,q^T -> yb) || kv gemm (planb,k/v^T -> kvc)
  mega_gemmC2<<<768, 256, 0, stream>>>(lnb, qwt, q_b, yb, planb, kwt, biaskv, kvc);
  // D7: cross attn (yb,kvc -> co) || ca^T (->rega+4)
  mega_attn_wt<false, false><<<512 + 256, 256, 0, stream>>>(
      yb, 1024, 0, kvc, 0, kvc, 1024, 2048, 2048, 512, co, 1024, 0.125f,
      ca_w, caT, nullptr, nullptr);
  // D8: ca gemm (xw += co*W) || mp^T -> yb (qx dead)
  mega_gemmB2<<<512 + 1024, 256, 0, stream>>>(co, caT, ca_b, xw, mp_w, mpT);
  // D9: ln3
  k_ln<<<4096, 256, 0, stream>>>(xw, ln3_g, ln3_b, lnb);
  // D10: fc gemm (lnb, fc^T -> hmid, gelu)
  k_gemm8<2><<<256, 512, 0, stream>>>(lnb, fcT, fc_b, hmid, 4096, 4096, 1024);
  // D11: mlp_proj gemm (hmid, mp^T -> xw +=)
  k_gemm_s<1><<<512, 256, 0, stream>>>(hmid, mpT, mp_b, xw, 4096, 1024, 4096, nullptr);
}

// Round 16
// 295.465 us; speedup vs baseline: 1.0100x; 1.0100x over previous
//
#include <hip/hip_runtime.h>
#include <stdint.h>

typedef __bf16 bf16;
typedef __bf16 bf16x4 __attribute__((ext_vector_type(4)));
typedef __bf16 bf16x8 __attribute__((ext_vector_type(8)));
typedef float  f32x4  __attribute__((ext_vector_type(4)));

#define DEVI __device__ __forceinline__

DEVI void gll16(const void* g, void* l) {
  __builtin_amdgcn_global_load_lds(
      (const __attribute__((address_space(1))) void*)g,
      (__attribute__((address_space(3))) void*)l,
      16, 0, 0);
}

DEVI f32x4 mfma16(bf16x8 a, bf16x8 b, f32x4 c) {
  return __builtin_amdgcn_mfma_f32_16x16x32_bf16(a, b, c, 0, 0, 0);
}

// ------------- weight transpose body: fp32 [K][N] -> bf16 W^T [N][K], 64x64 tile -------------
DEVI void wt_body(char* arena, const float* __restrict__ W, bf16* __restrict__ WT,
                  int K, int N, int bx, int by, int tid) {
  float (*t)[65] = reinterpret_cast<float(*)[65]>(arena);   // 64x65 fp32 = 16640 B
  int bn = bx * 64, bk = by * 64;
  int tx = tid & 63, ty = tid >> 6;
#pragma unroll
  for (int i = 0; i < 16; ++i)
    t[ty + i * 4][tx] = W[(size_t)(bk + ty + i * 4) * N + bn + tx];
  __syncthreads();
#pragma unroll
  for (int i = 0; i < 16; ++i)
    WT[(size_t)(bn + ty + i * 4) * K + bk + tx] = (bf16)t[tx][ty + i * 4];
}

// ---------------- layernorm body (C=1024) fp32 -> bf16 ----------------
DEVI void ln_body(char* arena, const float* __restrict__ x, const float* __restrict__ g,
                  const float* __restrict__ b, bf16* __restrict__ out, int row, int tid) {
  float* ps  = (float*)arena;
  float* psq = ps + 4;
  f32x4 v = ((const f32x4*)(x + (size_t)row * 1024))[tid];
  float s = v[0] + v[1] + v[2] + v[3];
  float sq = v[0]*v[0] + v[1]*v[1] + v[2]*v[2] + v[3]*v[3];
#pragma unroll
  for (int m = 1; m < 64; m <<= 1) {
    s  += __shfl_xor(s, m, 64);
    sq += __shfl_xor(sq, m, 64);
  }
  int w = tid >> 6;
  if ((tid & 63) == 0) { ps[w] = s; psq[w] = sq; }
  __syncthreads();
  s  = ps[0] + ps[1] + ps[2] + ps[3];
  sq = psq[0] + psq[1] + psq[2] + psq[3];
  float mean = s * (1.f / 1024.f);
  float rs = rsqrtf(sq * (1.f / 1024.f) - mean * mean + 1e-5f);
  f32x4 gv = ((const f32x4*)g)[tid];
  f32x4 bv = ((const f32x4*)b)[tid];
  bf16x4 o;
#pragma unroll
  for (int i = 0; i < 4; ++i) o[i] = (bf16)((v[i] - mean) * rs * gv[i] + bv[i]);
  ((bf16x4*)(out + (size_t)row * 1024))[tid] = o;
}

__global__ __launch_bounds__(256)
void k_ln(const float* __restrict__ x, const float* __restrict__ g,
          const float* __restrict__ b, bf16* __restrict__ out) {
  __shared__ __align__(16) char arena[64];
  ln_body(arena, x, g, b, out, blockIdx.x, threadIdx.x);
}

// mega #1: ln1 (4096) + c_attn^T (768) + plan conv (1024) + bias concat (8)
__global__ __launch_bounds__(256)
void mega_misc(const float* __restrict__ x, const float* __restrict__ g,
               const float* __restrict__ b, bf16* __restrict__ out,
               const float* __restrict__ W, bf16* __restrict__ WT,
               const float* __restrict__ plan, bf16* __restrict__ planb,
               const float* __restrict__ kb, const float* __restrict__ vb,
               float* __restrict__ biaskv) {
  __shared__ __align__(16) char arena[16640];
  const int bid = blockIdx.x, tid = threadIdx.x;
  if (bid < 4096) {
    ln_body(arena, x, g, b, out, bid, tid);
  } else if (bid < 4864) {
    int wid = bid - 4096;
    wt_body(arena, W, WT, 1024, 3072, wid % 48, wid / 48, tid);
  } else if (bid < 5888) {
    int i = (bid - 4864) * 256 + tid;
    f32x4 v = ((const f32x4*)plan)[i];
    bf16x4 o;
    o[0] = (bf16)v[0]; o[1] = (bf16)v[1]; o[2] = (bf16)v[2]; o[3] = (bf16)v[3];
    ((bf16x4*)planb)[i] = o;
  } else {
    int i = (bid - 5888) * 256 + tid;
    biaskv[i] = i < 1024 ? kb[i] : vb[i - 1024];
  }
}

// ---------------- GEMM small-tile body: BM=64 BN=128 BK=64, 2-phase ----------------
// EPI 0: bf16 out.  EPI 1: fp32 out += v.  EPI 2: gelu->bf16.  EPI 3: out = Xres + v.
template <int EPI>
DEVI void gemm_s_body(char* arena, const bf16* __restrict__ A, const bf16* __restrict__ BT,
                      const float* __restrict__ bias, void* __restrict__ Cout,
                      int M, int N, int K, const float* __restrict__ Xres,
                      int nwg, int bid) {
  char (*SA)[8192]  = reinterpret_cast<char(*)[8192]>(arena);
  char (*SB)[16384] = reinterpret_cast<char(*)[16384]>(arena + 16384);
  const int tid = threadIdx.x;
  const int lane = tid & 63;
  const int w = tid >> 6;
  const int wr = w >> 1, wc = w & 1;
  const int lr = lane & 15, lg = lane >> 4;
  const int nk = K >> 6;

  const int q = nwg >> 3, r = nwg & 7;
  const int xcd = bid & 7, loc = bid >> 3;
  const int wg = (xcd < r ? xcd * (q + 1) : r * (q + 1) + (xcd - r) * q) + loc;
  const int gy = M >> 6;
  const int m0 = (wg % gy) << 6, n0 = (wg / gy) << 7;

  const int c8 = tid & 7;
  const int hrb = tid >> 3;
  auto stgA = [&](int buf, int ktc) {
#pragma unroll
    for (int i = 0; i < 2; ++i) {
      int hr = i * 32 + hrb;
      const bf16* s = A + (size_t)(m0 + hr) * K + ((size_t)ktc << 6) + ((c8 ^ (hr & 7)) << 3);
      gll16(s, &SA[buf][(i * 256 + tid) * 16]);
    }
  };
  auto stgB = [&](int buf, int ktc) {
#pragma unroll
    for (int i = 0; i < 4; ++i) {
      int hr = i * 32 + hrb;
      const bf16* s = BT + (size_t)(n0 + hr) * K + ((size_t)ktc << 6) + ((c8 ^ (hr & 7)) << 3);
      gll16(s, &SB[buf][(i * 256 + tid) * 16]);
    }
  };
  auto rdf = [&](const char* base, int rloc, int ks) -> bf16x8 {
    return *(const bf16x8*)(base + rloc * 128 + (((ks << 6) + (lg << 4)) ^ ((rloc & 7) << 4)));
  };

  f32x4 acc[2][4] = {};

  stgA(0, 0); stgB(0, 0);
  __syncthreads();
  for (int kt = 0; kt < nk; ++kt) {
    const int cur = kt & 1;
    if (kt + 1 < nk) { stgA(cur ^ 1, kt + 1); stgB(cur ^ 1, kt + 1); }
    bf16x8 af[2][2], bfr[4][2];
#pragma unroll
    for (int i = 0; i < 2; ++i)
#pragma unroll
      for (int ks = 0; ks < 2; ++ks)
        af[i][ks] = rdf(SA[cur], wr * 32 + i * 16 + lr, ks);
#pragma unroll
    for (int j = 0; j < 4; ++j)
#pragma unroll
      for (int ks = 0; ks < 2; ++ks)
        bfr[j][ks] = rdf(SB[cur], wc * 64 + j * 16 + lr, ks);
#pragma unroll
    for (int i = 0; i < 2; ++i)
#pragma unroll
      for (int j = 0; j < 4; ++j)
#pragma unroll
        for (int ks = 0; ks < 2; ++ks)
          acc[i][j] = mfma16(af[i][ks], bfr[j][ks], acc[i][j]);
    __syncthreads();
  }

  float* of = (float*)Cout;
  bf16*  ob = (bf16*)Cout;
#pragma unroll
  for (int j = 0; j < 4; ++j) {
    int gn = n0 + wc * 64 + j * 16 + lr;
    float bv = bias[gn];
#pragma unroll
    for (int i = 0; i < 2; ++i) {
      int gmb = m0 + wr * 32 + i * 16 + lg * 4;
#pragma unroll
      for (int rr = 0; rr < 4; ++rr) {
        size_t idx = (size_t)(gmb + rr) * N + gn;
        float v = acc[i][j][rr] + bv;
        if (EPI == 0) ob[idx] = (bf16)v;
        else if (EPI == 1) of[idx] += v;
        else if (EPI == 3) of[idx] = Xres[idx] + v;
        else {
          float ge = 0.5f * v * (1.f + erff(v * 0.70710678f));
          ob[idx] = (bf16)ge;
        }
      }
    }
  }
}

template <int EPI>
__global__ __launch_bounds__(256, 3)
void k_gemm_s(const bf16* __restrict__ A, const bf16* __restrict__ BT,
              const float* __restrict__ bias, void* __restrict__ Cout,
              int M, int N, int K, const float* __restrict__ Xres) {
  __shared__ __align__(16) char arena[49152];
  gemm_s_body<EPI>(arena, A, BT, bias, Cout, M, N, K, Xres, gridDim.x, blockIdx.x);
}

// mega: aproj-gemm (512) + q/k/v weight transposes (768)
__global__ __launch_bounds__(256, 3)
void mega_gemmA2(const bf16* __restrict__ A, const bf16* __restrict__ BT,
                 const float* __restrict__ bias, void* __restrict__ Cout,
                 const float* __restrict__ Xres,
                 const float* __restrict__ qw, bf16* __restrict__ qwt,
                 const float* __restrict__ kw, bf16* __restrict__ kwt,
                 const float* __restrict__ vw, bf16* __restrict__ vwt) {
  __shared__ __align__(16) char arena[49152];
  if ((int)blockIdx.x < 512) {
    gemm_s_body<3>(arena, A, BT, bias, Cout, 4096, 1024, 1024, Xres, 512, blockIdx.x);
  } else {
    int wid = blockIdx.x - 512;
    const float* W = wid < 256 ? qw : (wid < 512 ? kw : vw);
    bf16* WT = wid < 256 ? qwt : (wid < 512 ? kwt : vwt);
    int sub = wid & 255;
    wt_body(arena, W, WT, 1024, 1024, sub & 15, sub >> 4, threadIdx.x);
  }
}

// mega: ca-gemm (512) + mlp_proj weight transpose (1024, K=4096)
__global__ __launch_bounds__(256, 3)
void mega_gemmB2(const bf16* __restrict__ A, const bf16* __restrict__ BT,
                 const float* __restrict__ bias, void* __restrict__ Cout,
                 const float* __restrict__ mw, bf16* __restrict__ mwt) {
  __shared__ __align__(16) char arena[49152];
  if ((int)blockIdx.x < 512) {
    gemm_s_body<1>(arena, A, BT, bias, Cout, 4096, 1024, 1024, nullptr, 512, blockIdx.x);
  } else {
    int wid = blockIdx.x - 512;
    wt_body(arena, mw, mwt, 4096, 1024, wid & 15, wid >> 4, threadIdx.x);
  }
}

// mega: qx-gemm (512) + kv-gemm (256) — mutually independent
__global__ __launch_bounds__(256, 3)
void mega_gemmC2(const bf16* __restrict__ Aq, const bf16* __restrict__ qwt,
                 const float* __restrict__ qb, void* __restrict__ qxo,
                 const bf16* __restrict__ Ap, const bf16* __restrict__ kwt,
                 const float* __restrict__ bkv, void* __restrict__ kvo) {
  __shared__ __align__(16) char arena[49152];
  if ((int)blockIdx.x < 512) {
    gemm_s_body<0>(arena, Aq, qwt, qb, qxo, 4096, 1024, 1024, nullptr, 512, blockIdx.x);
  } else {
    gemm_s_body<0>(arena, Ap, kwt, bkv, kvo, 1024, 2048, 1024, nullptr, 256, blockIdx.x - 512);
  }
}

// ---------------- GEMM 256x256 8-phase counted-vmcnt ----------------
template <int EPI>
__global__ __launch_bounds__(512, 2)
void k_gemm8(const bf16* __restrict__ A, const bf16* __restrict__ BT,
             const float* __restrict__ bias, void* __restrict__ Cout,
             int M, int N, int K) {
  __shared__ __align__(16) char SA[2][2][16384];
  __shared__ __align__(16) char SB[2][2][16384];
  const int tid = threadIdx.x;
  const int lane = tid & 63;
  const int w = tid >> 6;
  const int wm = w >> 2, wn = w & 3;
  const int lr = lane & 15, lg = lane >> 4;
  const int nk = K >> 6;

  const int nwg = gridDim.x;
  const int q = nwg >> 3, r = nwg & 7;
  const int xcd = blockIdx.x & 7, loc = blockIdx.x >> 3;
  const int wg = (xcd < r ? xcd * (q + 1) : r * (q + 1) + (xcd - r) * q) + loc;
  const int gy = M >> 8;
  const int m0 = (wg % gy) << 8, n0 = (wg / gy) << 8;

  const int c8 = tid & 7;
  auto stg = [&](char* dst, const bf16* src0, int base0, int half, int ktc) {
#pragma unroll
    for (int i = 0; i < 2; ++i) {
      int hr = i * 64 + (tid >> 3);
      const bf16* s = src0 + (size_t)(base0 + half * 128 + hr) * K + ((size_t)ktc << 6)
                    + ((c8 ^ (hr & 7)) << 3);
      gll16(s, dst + (i * 512 + tid) * 16);
    }
  };
  auto rdf = [&](const char* hbase, int rloc, int ks) -> bf16x8 {
    return *(const bf16x8*)(hbase + rloc * 128 + (((ks << 6) + (lg << 4)) ^ ((rloc & 7) << 4)));
  };

  f32x4 acc[8][4] = {};
  bf16x8 af[4][2], b0f[2][2], b1f[2][2];

  stg(SA[0][0], A, m0, 0, 0);
  stg(SB[0][0], BT, n0, 0, 0);
  stg(SB[0][1], BT, n0, 1, 0);
  stg(SA[0][1], A, m0, 1, 0);
  stg(SA[1][0], A, m0, 0, 1);
  stg(SB[1][0], BT, n0, 0, 1);
  asm volatile("s_waitcnt vmcnt(8)" ::: "memory");
  __builtin_amdgcn_s_barrier();

  for (int kt = 0; kt < nk; ++kt) {
    const int cur = kt & 1;
    const char* hA0 = SA[cur][0]; const char* hA1 = SA[cur][1];
    const char* hB0 = SB[cur][0]; const char* hB1 = SB[cur][1];
    const int tn  = (kt + 1 < nk) ? kt + 1 : nk - 1;
    const int tn2 = (kt + 2 < nk) ? kt + 2 : nk - 1;

    stg(SB[(kt + 1) & 1][1], BT, n0, 1, tn);
    asm volatile("s_waitcnt vmcnt(8)" ::: "memory");
#pragma unroll
    for (int i = 0; i < 4; ++i) {
      int rl = i * 32 + wm * 16 + lr;
#pragma unroll
      for (int ks = 0; ks < 2; ++ks) af[i][ks] = rdf(hA0, rl, ks);
    }
#pragma unroll
    for (int j = 0; j < 2; ++j) {
      int rl = j * 64 + wn * 16 + lr;
#pragma unroll
      for (int ks = 0; ks < 2; ++ks) b0f[j][ks] = rdf(hB0, rl, ks);
    }
    __builtin_amdgcn_s_barrier();
    __builtin_amdgcn_s_setprio(1);
#pragma unroll
    for (int i = 0; i < 4; ++i)
#pragma unroll
      for (int j = 0; j < 2; ++j)
#pragma unroll
        for (int ks = 0; ks < 2; ++ks)
          acc[i][j] = mfma16(af[i][ks], b0f[j][ks], acc[i][j]);
    __builtin_amdgcn_s_setprio(0);

    stg(SA[(kt + 1) & 1][1], A, m0, 1, tn);
    asm volatile("s_waitcnt vmcnt(8)" ::: "memory");
#pragma unroll
    for (int j = 0; j < 2; ++j) {
      int rl = j * 64 + wn * 16 + lr;
#pragma unroll
      for (int ks = 0; ks < 2; ++ks) b1f[j][ks] = rdf(hB1, rl, ks);
    }
    __builtin_amdgcn_s_barrier();
    __builtin_amdgcn_s_setprio(1);
#pragma unroll
    for (int i = 0; i < 4; ++i)
#pragma unroll
      for (int j = 0; j < 2; ++j)
#pragma unroll
        for (int ks = 0; ks < 2; ++ks)
          acc[i][2 + j] = mfma16(af[i][ks], b1f[j][ks], acc[i][2 + j]);
    __builtin_amdgcn_s_setprio(0);

    stg(SA[cur][0], A, m0, 0, tn2);
#pragma unroll
    for (int i = 0; i < 4; ++i) {
      int rl = i * 32 + wm * 16 + lr;
#pragma unroll
      for (int ks = 0; ks < 2; ++ks) af[i][ks] = rdf(hA1, rl, ks);
    }
    __builtin_amdgcn_s_barrier();
    __builtin_amdgcn_s_setprio(1);
#pragma unroll
    for (int i = 0; i < 4; ++i)
#pragma unroll
      for (int j = 0; j < 2; ++j)
#pragma unroll
        for (int ks = 0; ks < 2; ++ks)
          acc[4 + i][j] = mfma16(af[i][ks], b0f[j][ks], acc[4 + i][j]);
    __builtin_amdgcn_s_setprio(0);

    stg(SB[cur][0], BT, n0, 0, tn2);
    asm volatile("s_waitcnt vmcnt(8)" ::: "memory");
    __builtin_amdgcn_s_barrier();
    __builtin_amdgcn_s_setprio(1);
#pragma unroll
    for (int i = 0; i < 4; ++i)
#pragma unroll
      for (int j = 0; j < 2; ++j)
#pragma unroll
        for (int ks = 0; ks < 2; ++ks)
          acc[4 + i][2 + j] = mfma16(af[i][ks], b1f[j][ks], acc[4 + i][2 + j]);
    __builtin_amdgcn_s_setprio(0);
  }

  float* of = (float*)Cout;
  bf16*  ob = (bf16*)Cout;
#pragma unroll
  for (int ni = 0; ni < 4; ++ni) {
    int gn = n0 + (ni >> 1) * 128 + (ni & 1) * 64 + wn * 16 + lr;
    float bv = bias[gn];
#pragma unroll
    for (int mi = 0; mi < 8; ++mi) {
      int gmb = m0 + (mi >> 2) * 128 + (mi & 3) * 32 + wm * 16 + lg * 4;
#pragma unroll
      for (int rr = 0; rr < 4; ++rr) {
        size_t idx = (size_t)(gmb + rr) * N + gn;
        float v = acc[mi][ni][rr] + bv;
        if (EPI == 0) ob[idx] = (bf16)v;
        else if (EPI == 1) of[idx] += v;
        else {
          float ge = 0.5f * v * (1.f + erff(v * 0.70710678f));
          ob[idx] = (bf16)ge;
        }
      }
    }
  }
}

// ---------------- fused flash attention body (r4 champion logic) ----------------
template <bool CAUSAL>
DEVI void attn_body(char* arena, int id,
                    const bf16* __restrict__ Qb, int ldq, int qcol0,
                    const bf16* __restrict__ Kb, int kcol0,
                    const bf16* __restrict__ Vb, int vcol0,
                    int ldkv, int qlen, int kvlen,
                    bf16* __restrict__ Ob, int ldo, float scale) {
  char (*Klds)[8192]   = reinterpret_cast<char(*)[8192]>(arena);
  bf16 (*VT)[64][68]   = reinterpret_cast<bf16(*)[64][68]>(arena + 16384);
  const int tid = threadIdx.x;
  const int lane = tid & 63;
  const int w = tid >> 6;
  const int lr = lane & 15, lg = lane >> 4;

  int h, b, qt;
  if (CAUSAL) {
    int low = id & 255;
    h = low & 15; b = (low >> 4) & 1;
    int q3 = low >> 5;
    qt = (id >> 8) ? (8 + q3) : (7 - q3);
  } else {
    h = id & 15; b = (id >> 4) & 1; qt = id >> 5;
  }

  const int qbase = qt * 128;
  const int kvbase = b * kvlen;
  const int nkv = CAUSAL ? (2 * qt + 2) : (kvlen >> 6);
  const int mask_from = CAUSAL ? (nkv - 2) : 0x7fffffff;

  bf16x8 qf[2][2];
#pragma unroll
  for (int g = 0; g < 2; ++g)
#pragma unroll
    for (int kk = 0; kk < 2; ++kk)
      qf[g][kk] = *(const bf16x8*)(Qb + (size_t)(b * qlen + qbase + w * 32 + g * 16 + lr) * ldq
                                   + qcol0 + h * 64 + kk * 32 + lg * 8);

  f32x4 o[2][4] = {};
  float mrun[2] = {-3.0e38f, -3.0e38f};
  float lsum[2] = {0.f, 0.f};

  bf16x8 vr0, vr1;
  const int vkv = lane;
  const int vd0 = (tid >> 6) * 16;
  const bf16* Vbase = Vb + vcol0 + h * 64 + vd0;

  auto stageK = [&](int buf, int kvt) {
#pragma unroll
    for (int t = 0; t < 2; ++t) {
      int r = t * 32 + (tid >> 3);
      int pb = (tid & 7) * 16;
      const char* gs = (const char*)(Kb + (size_t)(kvbase + kvt * 64 + r) * ldkv + kcol0 + h * 64)
                       + (pb ^ ((r & 7) << 4));
      gll16(gs, &Klds[buf][t * 4096 + tid * 16]);
    }
  };
  auto loadV = [&](int kvt) {
    const bf16* vp = Vbase + (size_t)(kvbase + kvt * 64 + vkv) * ldkv;
    vr0 = *(const bf16x8*)vp;
    vr1 = *(const bf16x8*)(vp + 8);
  };
  auto writeV = [&](int buf) {
#pragma unroll
    for (int i = 0; i < 8; ++i) VT[buf][vd0 + i][vkv] = vr0[i];
#pragma unroll
    for (int i = 0; i < 8; ++i) VT[buf][vd0 + 8 + i][vkv] = vr1[i];
  };

  stageK(0, 0);
  loadV(0);
  writeV(0);
  __syncthreads();

  int cur = 0;
  for (int kvt = 0; kvt < nkv; ++kvt) {
    if (kvt + 1 < nkv) { stageK(cur ^ 1, kvt + 1); loadV(kvt + 1); }

    f32x4 s[2][4] = {};
#pragma unroll
    for (int sub = 0; sub < 4; ++sub) {
      int row = sub * 16 + lr;
#pragma unroll
      for (int kk = 0; kk < 2; ++kk) {
        bf16x8 kf = *(const bf16x8*)&Klds[cur][(row << 7) + ((kk * 64 + lg * 16) ^ ((row & 7) << 4))];
        s[0][sub] = mfma16(kf, qf[0][kk], s[0][sub]);
        s[1][sub] = mfma16(kf, qf[1][kk], s[1][sub]);
      }
    }

    const bool domask = CAUSAL && (kvt >= mask_from);
    bf16x8 pa[2][2];
#pragma unroll
    for (int g = 0; g < 2; ++g) {
      const int qg = qbase + w * 32 + g * 16 + lr;
      float pmax = -3.0e38f;
#pragma unroll
      for (int sub = 0; sub < 4; ++sub)
#pragma unroll
        for (int j = 0; j < 4; ++j) {
          float v = s[g][sub][j] * scale;
          if (domask) {
            int kvg = kvt * 64 + sub * 16 + lg * 4 + j;
            if (kvg > qg) v = -3.0e38f;
          }
          s[g][sub][j] = v;
          pmax = fmaxf(pmax, v);
        }
      pmax = fmaxf(pmax, __shfl_xor(pmax, 16, 64));
      pmax = fmaxf(pmax, __shfl_xor(pmax, 32, 64));
      float mnew = mrun[g];
      if (__any(pmax - mrun[g] > 8.f)) {
        mnew = fmaxf(mrun[g], pmax);
        float alpha = __expf(mrun[g] - mnew);
        lsum[g] *= alpha;
        float al[4];
#pragma unroll
        for (int j = 0; j < 4; ++j) {
          int src = (lane & 48) | (lg * 4 + j);
          al[j] = __int_as_float(__builtin_amdgcn_ds_bpermute(src << 2, __float_as_int(alpha)));
        }
#pragma unroll
        for (int dt = 0; dt < 4; ++dt)
#pragma unroll
          for (int j = 0; j < 4; ++j) o[g][dt][j] *= al[j];
      }
      float psum = 0.f;
#pragma unroll
      for (int sub = 0; sub < 4; ++sub)
#pragma unroll
        for (int j = 0; j < 4; ++j) {
          float p = __expf(s[g][sub][j] - mnew);
          s[g][sub][j] = p;
          psum += p;
        }
      psum += __shfl_xor(psum, 16, 64);
      psum += __shfl_xor(psum, 32, 64);
      lsum[g] += psum;
      mrun[g] = mnew;
#pragma unroll
      for (int sp = 0; sp < 2; ++sp) {
#pragma unroll
        for (int j = 0; j < 4; ++j) {
          pa[g][sp][j]     = (bf16)s[g][2 * sp][j];
          pa[g][sp][4 + j] = (bf16)s[g][2 * sp + 1][j];
        }
      }
    }

#pragma unroll
    for (int sp = 0; sp < 2; ++sp) {
#pragma unroll
      for (int dt = 0; dt < 4; ++dt) {
        int d = dt * 16 + lr;
        bf16x4 va  = *(const bf16x4*)&VT[cur][d][sp * 32 + lg * 4];
        bf16x4 vb2 = *(const bf16x4*)&VT[cur][d][sp * 32 + 16 + lg * 4];
        bf16x8 vf = __builtin_shufflevector(va, vb2, 0, 1, 2, 3, 4, 5, 6, 7);
        o[0][dt] = mfma16(pa[0][sp], vf, o[0][dt]);
        o[1][dt] = mfma16(pa[1][sp], vf, o[1][dt]);
      }
    }

    if (kvt + 1 < nkv) writeV(cur ^ 1);
    __syncthreads();
    cur ^= 1;
  }

#pragma unroll
  for (int g = 0; g < 2; ++g) {
    float il[4];
#pragma unroll
    for (int j = 0; j < 4; ++j) {
      int src = (lane & 48) | (lg * 4 + j);
      float ls = __int_as_float(__builtin_amdgcn_ds_bpermute(src << 2, __float_as_int(lsum[g])));
      il[j] = 1.0f / ls;
    }
#pragma unroll
    for (int dt = 0; dt < 4; ++dt)
#pragma unroll
      for (int j = 0; j < 4; ++j) {
        int gq = b * qlen + qbase + w * 32 + g * 16 + lg * 4 + j;
        Ob[(size_t)gq * ldo + h * 64 + dt * 16 + lr] = (bf16)(o[g][dt][j] * il[j]);
      }
  }
}

// mega: attention (512) + wt1 1024x1024 (256) + optional wt2 1024x4096 (1024)
template <bool CAUSAL, bool WT2>
__global__ __launch_bounds__(256)
void mega_attn_wt(const bf16* __restrict__ Qb, int ldq, int qcol0,
                  const bf16* __restrict__ Kb, int kcol0,
                  const bf16* __restrict__ Vb, int vcol0,
                  int ldkv, int qlen, int kvlen,
                  bf16* __restrict__ Ob, int ldo, float scale,
                  const float* __restrict__ W1, bf16* __restrict__ WT1,
                  const float* __restrict__ W2, bf16* __restrict__ WT2b) {
  __shared__ __align__(16) char arena[33792];
  if ((int)blockIdx.x < 512) {
    attn_body<CAUSAL>(arena, blockIdx.x, Qb, ldq, qcol0, Kb, kcol0, Vb, vcol0,
                      ldkv, qlen, kvlen, Ob, ldo, scale);
  } else if ((int)blockIdx.x < 768) {
    int wid = blockIdx.x - 512;
    wt_body(arena, W1, WT1, 1024, 1024, wid & 15, wid >> 4, threadIdx.x);
  } else if (WT2) {
    int wid = blockIdx.x - 768;   // 1024 blocks: fc_w [1024][4096] -> [4096][1024]
    wt_body(arena, W2, WT2b, 1024, 4096, wid & 63, wid >> 6, threadIdx.x);
  }
}

// ---------------- host orchestration ----------------
extern "C" void kernel_launch(void* const* d_in, const int* in_sizes, int n_in,
                              void* d_out, int out_size, void* d_ws, size_t ws_size,
                              hipStream_t stream) {
  (void)in_sizes; (void)n_in; (void)out_size; (void)ws_size;
  const float* x        = (const float*)d_in[0];
  const float* plan     = (const float*)d_in[1];
  const float* ln1_g    = (const float*)d_in[2];
  const float* ln1_b    = (const float*)d_in[3];
  const float* c_attn_w = (const float*)d_in[4];
  const float* c_attn_b = (const float*)d_in[5];
  const float* aproj_w  = (const float*)d_in[6];
  const float* aproj_b  = (const float*)d_in[7];
  const float* ln2_g    = (const float*)d_in[8];
  const float* ln2_b    = (const float*)d_in[9];
  const float* q_w      = (const float*)d_in[10];
  const float* q_b      = (const float*)d_in[11];
  const float* k_w      = (const float*)d_in[12];
  const float* k_b      = (const float*)d_in[13];
  const float* v_w      = (const float*)d_in[14];
  const float* v_b      = (const float*)d_in[15];
  const float* ca_w     = (const float*)d_in[16];
  const float* ca_b     = (const float*)d_in[17];
  const float* ln3_g    = (const float*)d_in[18];
  const float* ln3_b    = (const float*)d_in[19];
  const float* fc_w     = (const float*)d_in[20];
  const float* fc_b     = (const float*)d_in[21];
  const float* mp_w     = (const float*)d_in[22];
  const float* mp_b     = (const float*)d_in[23];

  char* ws = (char*)d_ws;
  // layout (MiB): [0-8) wbuf: c_attn^T then fc^T | [8-16) lnb: also aproj^T/ca^T home
  // [16-18) planb | [18-26) yb: attn-out/qx/mp^T | [26-58) rega | 58+ biaskv
  bf16*  wbuf   = (bf16*)(ws);
  bf16*  lnb    = (bf16*)(ws + (8ull << 20));
  bf16*  planb  = (bf16*)(ws + (16ull << 20));
  bf16*  yb     = (bf16*)(ws + (18ull << 20));
  char*  rega   = ws + (26ull << 20);
  float* biaskv = (float*)(ws + (58ull << 20));
  bf16* qkv  = (bf16*)rega;                     // 24 MiB (self phase)
  bf16* qwt  = (bf16*)rega;                     // cross phase: q^T
  bf16* kwt  = (bf16*)(rega + (2ull << 20));    // k^T | v^T contiguous (kv fused gemm)
  bf16* kvc  = (bf16*)(rega + (8ull << 20));
  bf16* co   = (bf16*)(rega + (12ull << 20));
  bf16* hmid = (bf16*)rega;                     // 32 MiB (MLP phase)
  bf16* aprojT = lnb;                           // 2 MiB, lives D3->D4 (lnb dead)
  bf16* caT    = lnb;                           // 2 MiB, lives D7->D8
  bf16* fcT    = wbuf;                          // 8 MiB, written D3, read D10
  bf16* mpT    = yb;                            // 8 MiB, written D8, read D11
  float* xw = (float*)d_out;

  // D1: ln1 || c_attn^T || plan conv || bias concat
  mega_misc<<<5896, 256, 0, stream>>>(x, ln1_g, ln1_b, lnb, c_attn_w, wbuf,
                                      plan, planb, k_b, v_b, biaskv);
  // D2: qkv gemm
  k_gemm8<0><<<192, 512, 0, stream>>>(lnb, wbuf, c_attn_b, qkv, 4096, 3072, 1024);
  // D3: causal attn || aproj^T(->lnb) || fc^T(->wbuf; c_attn^T consumed)
  mega_attn_wt<true, true><<<512 + 256 + 1024, 256, 0, stream>>>(
      qkv, 3072, 0, qkv, 1024, qkv, 2048, 3072, 2048, 2048, yb, 1024, 0.125f,
      aproj_w, aprojT, fc_w, fcT);
  // D4: aproj gemm (xw = x + yb*W) || q/k/v^T -> rega (qkv consumed)
  mega_gemmA2<<<512 + 768, 256, 0, stream>>>(yb, aprojT, aproj_b, xw, x,
                                             q_w, qwt, k_w, kwt, v_w, kwt + (1u << 20));
  // D5: ln2
  k_ln<<<4096, 256, 0, stream>>>(xw, ln2_g, ln2_b, lnb);
  // D6: qx gemm (lnb,qwt -> yb) || kv gemm (planb,kwt -> kvc)
  mega_gemmC2<<<768, 256, 0, stream>>>(lnb, qwt, q_b, yb, planb, kwt, biaskv, kvc);
  // D7: cross attn (yb,kvc -> co) || ca^T (->lnb; qx consumed)
  mega_attn_wt<false, false><<<512 + 256, 256, 0, stream>>>(
      yb, 1024, 0, kvc, 0, kvc, 1024, 2048, 2048, 512, co, 1024, 0.125f,
      ca_w, caT, nullptr, nullptr);
  // D8: ca gemm (xw += co*W) || mp^T -> yb
  mega_gemmB2<<<512 + 1024, 256, 0, stream>>>(co, caT, ca_b, xw, mp_w, mpT);
  // D9: ln3
  k_ln<<<4096, 256, 0, stream>>>(xw, ln3_g, ln3_b, lnb);
  // D10: fc gemm (lnb, fc^T -> hmid, gelu)
  k_gemm8<2><<<256, 512, 0, stream>>>(lnb, fcT, fc_b, hmid, 4096, 4096, 1024);
  // D11: mlp_proj gemm (hmid, mp^T -> xw +=)
  k_gemm_s<1><<<512, 256, 0, stream>>>(hmid, mpT, mp_b, xw, 4096, 1024, 4096, nullptr);
}